// Round 7
// baseline (231.756 us; speedup 1.0000x reference)
//
#include <hip/hip_runtime.h>

#define N 4096
#define D 512
#define BM 64
#define KS 8
#define CHUNK (N / KS)          // 512 keys per block
#define NT (CHUNK / 64)         // 8 key-tiles (64 keys each) per block
#define NKT (N / 64)            // 64 key tiles total
#define FRAG_SH 512             // shorts per 16x32 fragment (1 KB)
#define TILE_SH (64 * FRAG_SH)  // shorts per 64-key tile (64 KB)
#define PB_W 72                 // Pb row stride (shorts)

typedef __attribute__((ext_vector_type(8))) short short8;
typedef __attribute__((ext_vector_type(4))) float f32x4;

__device__ __forceinline__ unsigned short f2bf(float f) {
    unsigned int u = __float_as_uint(f);
    u = (u + 0x7FFFu + ((u >> 16) & 1u)) >> 16;
    return (unsigned short)u;
}
__device__ __forceinline__ unsigned short f2bf_rn(float f) {
    return (unsigned short)((__float_as_uint(f) + 0x8000u) >> 16);
}

// Fused prep: blocks [0,2048) cast+scale Q; blocks [2048,2176) build
// fragment-linear Kblk (QK^T B-frags) and Vblk (PV B-frags) from hist.
__global__ __launch_bounds__(256) void prep_all(const float* __restrict__ q,
                                                const float* __restrict__ hist,
                                                unsigned short* __restrict__ Qbf,
                                                unsigned short* __restrict__ Kblk,
                                                unsigned short* __restrict__ Vblk) {
    __shared__ unsigned short tile[32 * 512];
    const int bx = blockIdx.x;
    const int tid = threadIdx.x;
    if (bx < 2048) {
        int i = (bx * 256 + tid) * 4;
        const float s = 0.04419417382415922f;   // 1/sqrt(512) folded into Q
        float4 v = *(const float4*)(q + i);
        ushort4 o;
        o.x = f2bf(v.x * s); o.y = f2bf(v.y * s); o.z = f2bf(v.z * s); o.w = f2bf(v.w * s);
        *(ushort4*)(Qbf + i) = o;
        return;
    }
    const int b = bx - 2048;
    const int t = b >> 1;       // parent 64-key tile
    const int h = b & 1;        // 32-key half
    #pragma unroll
    for (int k = 0; k < 16; ++k) {
        int idx = tid + k * 256;
        int row = idx >> 7;
        int c4  = (idx & 127) << 2;
        float4 v = *(const float4*)(hist + (size_t)(t * 64 + h * 32 + row) * D + c4);
        ushort4 o;
        o.x = f2bf(v.x); o.y = f2bf(v.y); o.z = f2bf(v.z); o.w = f2bf(v.w);
        *(ushort4*)(tile + row * 512 + c4) = o;
    }
    __syncthreads();
    // Kblk frag f = kb*4 + wc (wc in {2h,2h+1}): B[n=key wc*16+l16][k=d kb*32+q4*8+j]
    #pragma unroll
    for (int k = 0; k < 8; ++k) {
        int s = tid + k * 256;
        int fl = s >> 6, lane = s & 63;
        int kb = fl >> 1, wcl = fl & 1, wc = 2 * h + wcl;
        int l16 = lane & 15, q4 = lane >> 4;
        short8 v = *(const short8*)(tile + (wcl * 16 + l16) * 512 + kb * 32 + q4 * 8);
        *(short8*)(Kblk + (size_t)t * TILE_SH + (size_t)(kb * 4 + wc) * FRAG_SH + lane * 8) = v;
    }
    // Vblk frag g = ks*32 + nb (ks == h): B[n=dcol nb*16+l16][k=key ks*32+q4*8+j]
    #pragma unroll
    for (int k = 0; k < 8; ++k) {
        int s = tid + k * 256;
        int nb = s >> 6, lane = s & 63;
        int g = h * 32 + nb;
        int l16 = lane & 15, q4 = lane >> 4;
        unsigned short tmp[8];
        #pragma unroll
        for (int j = 0; j < 8; ++j)
            tmp[j] = tile[(q4 * 8 + j) * 512 + nb * 16 + l16];
        *(short8*)(Vblk + (size_t)t * TILE_SH + (size_t)g * FRAG_SH + lane * 8) = *(const short8*)tmp;
    }
}

// Flash partial, LDS-minimal: K/V B-frags read DIRECTLY from fragment-linear
// global (coalesced dwordx4, L2-resident per-XCD chunk). LDS holds only the
// P C->A transform (10 KB), so barriers fence ~nothing; latency hidden by
// per-wave memory-level parallelism (32 indep loads per phase).
// 8 waves: wr=wv&1 (32-row strip), wc=wv>>1 (16-key col / 128-dcol strip).
__global__ __launch_bounds__(512) void flash_kernel(
    const unsigned short* __restrict__ Qbf,
    const unsigned short* __restrict__ Kblk,
    const unsigned short* __restrict__ Vblk,
    const float* __restrict__ times,
    const float* __restrict__ w1,
    const float* __restrict__ b1,
    const float* __restrict__ w2,
    const float* __restrict__ b2,
    unsigned short* __restrict__ opart,   // use_part: bf16 Opart[KS][N][D]
    float* __restrict__ dpart,            // dpart[KS][N] (or denom accumulator)
    float* __restrict__ oatomic,          // fallback fp32 accumulator
    int use_part)
{
    __shared__ unsigned short Pb[BM * PB_W];   // 9 KB
    __shared__ float lred[BM * 4];             // 1 KB

    const int tid  = threadIdx.x;
    const int wv   = tid >> 6;
    const int lane = tid & 63;
    const int q4   = lane >> 4;
    const int l16  = lane & 15;
    const int wr   = wv & 1;
    const int wc   = wv >> 1;     // 0..3
    const int bx   = blockIdx.x;
    const int chunk = bx & 7;     // XCD-affine: 1 MB K+V slab per XCD L2
    const int R0   = (bx >> 3) * BM;

    // Q A-frags register-resident: rows R0 + wr*32 + r2*16 + l16
    short8 qfrag[2][16];
    #pragma unroll
    for (int r2 = 0; r2 < 2; ++r2) {
        const unsigned short* qp = Qbf + (size_t)(R0 + wr * 32 + r2 * 16 + l16) * D + q4 * 8;
        #pragma unroll
        for (int kb = 0; kb < 16; ++kb)
            qfrag[r2][kb] = *(const short8*)(qp + kb * 32);
    }

    float tr[2][4];
    #pragma unroll
    for (int r2 = 0; r2 < 2; ++r2)
        #pragma unroll
        for (int ri = 0; ri < 4; ++ri)
            tr[r2][ri] = times[R0 + wr * 32 + r2 * 16 + q4 * 4 + ri];

    float w1v[8], b1v[8], w2v[8];
    #pragma unroll
    for (int k = 0; k < 8; ++k) { w1v[k] = w1[k]; b1v[k] = b1[k]; w2v[k] = w2[k]; }
    const float b2v = b2[0];
    bool fast = true;
    #pragma unroll
    for (int k = 0; k < 8; ++k) fast = fast && (b1v[k] == 0.0f);
    float C1 = 0.0f;
    #pragma unroll
    for (int k = 0; k < 8; ++k) C1 += w2v[k] * fmaxf(w1v[k], 0.0f);

    f32x4 of[2][8];
    #pragma unroll
    for (int r2 = 0; r2 < 2; ++r2)
        #pragma unroll
        for (int dt = 0; dt < 8; ++dt) of[r2][dt] = (f32x4){0.f, 0.f, 0.f, 0.f};
    float lacc[2][4] = {{0.f,0.f,0.f,0.f},{0.f,0.f,0.f,0.f}};

    for (int kt = 0; kt < NT; ++kt) {
        const int t64 = chunk * NT + kt;     // global 64-key tile index

        // ---- QK^T: B-frags straight from global Kblk (L2-hot, coalesced) ----
        const unsigned short* Kt = Kblk + (size_t)t64 * TILE_SH;
        f32x4 c[2] = { {0,0,0,0}, {0,0,0,0} };
        #pragma unroll
        for (int kb = 0; kb < 16; ++kb) {
            short8 b = *(const short8*)(Kt + (size_t)(kb * 4 + wc) * FRAG_SH + lane * 8);
            c[0] = __builtin_amdgcn_mfma_f32_16x16x32_bf16(qfrag[0][kb], b, c[0], 0, 0, 0);
            c[1] = __builtin_amdgcn_mfma_f32_16x16x32_bf16(qfrag[1][kb], b, c[1], 0, 0, 0);
        }

        // ---- time weight (collapsed MLP) + exp; P -> LDS (C->A transform) ----
        const float tc = times[t64 * 64 + wc * 16 + l16];
        #pragma unroll
        for (int r2 = 0; r2 < 2; ++r2) {
            #pragma unroll
            for (int ri = 0; ri < 4; ++ri) {
                float td = fabsf(tr[r2][ri] - tc);
                float a = fmaf(td, C1, b2v);
                if (!fast) {
                    a = b2v;
                    #pragma unroll
                    for (int k = 0; k < 8; ++k)
                        a += w2v[k] * fmaxf(fmaf(td, w1v[k], b1v[k]), 0.f);
                }
                float twt = __builtin_amdgcn_rcpf(1.0f + __expf(-a));
                float e = __expf(c[r2][ri] * twt);   // 1/sqrt(D) pre-folded into Q
                lacc[r2][ri] += e;
                Pb[(wr * 32 + r2 * 16 + q4 * 4 + ri) * PB_W + wc * 16 + l16] = f2bf_rn(e);
            }
        }
        __syncthreads();   // P visible

        // ---- PV: B-frags straight from global Vblk; 16 indep acc chains ----
        const unsigned short* Vt = Vblk + (size_t)t64 * TILE_SH;
        #pragma unroll
        for (int ks = 0; ks < 2; ++ks) {
            short8 a2[2];
            #pragma unroll
            for (int r2 = 0; r2 < 2; ++r2)
                a2[r2] = *(const short8*)(Pb + ((wr * 2 + r2) * 16 + l16) * PB_W + ks * 32 + q4 * 8);
            #pragma unroll
            for (int dt = 0; dt < 8; ++dt) {
                short8 b = *(const short8*)(Vt + (size_t)(ks * 32 + wc * 8 + dt) * FRAG_SH + lane * 8);
                of[0][dt] = __builtin_amdgcn_mfma_f32_16x16x32_bf16(a2[0], b, of[0][dt], 0, 0, 0);
                of[1][dt] = __builtin_amdgcn_mfma_f32_16x16x32_bf16(a2[1], b, of[1][dt], 0, 0, 0);
            }
        }
        __syncthreads();   // Pb readers done before next tile's writes
    }

    // ---- denominator partial: butterfly + cross-wave via lred ----
    float lrow[2][4];
    #pragma unroll
    for (int r2 = 0; r2 < 2; ++r2) {
        #pragma unroll
        for (int ri = 0; ri < 4; ++ri) {
            float v = lacc[r2][ri];
            v += __shfl_xor(v, 1);
            v += __shfl_xor(v, 2);
            v += __shfl_xor(v, 4);
            v += __shfl_xor(v, 8);
            lrow[r2][ri] = v;
        }
    }
    if (l16 == 0) {
        #pragma unroll
        for (int r2 = 0; r2 < 2; ++r2)
            #pragma unroll
            for (int ri = 0; ri < 4; ++ri)
                lred[(wr * 32 + r2 * 16 + q4 * 4 + ri) * 4 + wc] = lrow[r2][ri];
    }
    __syncthreads();
    if (tid < BM) {
        float s = lred[tid * 4 + 0] + lred[tid * 4 + 1] + lred[tid * 4 + 2] + lred[tid * 4 + 3];
        if (use_part) dpart[(size_t)chunk * N + R0 + tid] = s;
        else          atomicAdd(dpart + R0 + tid, s);
    }

    // ---- numerator partial: bf16 coalesced stores to per-chunk slab ----
    if (use_part) {
        unsigned short* obase = opart + (size_t)chunk * N * D;
        #pragma unroll
        for (int r2 = 0; r2 < 2; ++r2)
            #pragma unroll
            for (int ri = 0; ri < 4; ++ri) {
                const int row = R0 + wr * 32 + r2 * 16 + q4 * 4 + ri;
                #pragma unroll
                for (int dt = 0; dt < 8; ++dt)
                    obase[(size_t)row * D + wc * 128 + dt * 16 + l16] = f2bf_rn(of[r2][dt][ri]);
            }
    } else {
        #pragma unroll
        for (int r2 = 0; r2 < 2; ++r2)
            #pragma unroll
            for (int ri = 0; ri < 4; ++ri) {
                const int row = R0 + wr * 32 + r2 * 16 + q4 * 4 + ri;
                #pragma unroll
                for (int dt = 0; dt < 8; ++dt)
                    atomicAdd(oatomic + (size_t)row * D + wc * 128 + dt * 16 + l16,
                              of[r2][dt][ri]);
            }
    }
}

// out[i,:] = (sum_s bf16 Opart[s][i,:]) / (sum_s dpart[s][i])
__global__ void reduce_normalize_kernel(const unsigned short* __restrict__ Opart,
                                        const float* __restrict__ dpart,
                                        float* __restrict__ out) {
    int i = blockIdx.x * 256 + threadIdx.x;   // float4 index
    int row = i >> 7;
    float den = 0.f;
    #pragma unroll
    for (int s = 0; s < KS; ++s) den += dpart[(size_t)s * N + row];
    float inv = 1.0f / den;
    float4 acc = {0.f, 0.f, 0.f, 0.f};
    #pragma unroll
    for (int s = 0; s < KS; ++s) {
        ushort4 u = ((const ushort4*)(Opart + (size_t)s * N * D))[i];
        acc.x += __uint_as_float((unsigned)u.x << 16);
        acc.y += __uint_as_float((unsigned)u.y << 16);
        acc.z += __uint_as_float((unsigned)u.z << 16);
        acc.w += __uint_as_float((unsigned)u.w << 16);
    }
    acc.x *= inv; acc.y *= inv; acc.z *= inv; acc.w *= inv;
    ((float4*)out)[i] = acc;
}

// Atomic-fallback: out[i,:] /= denom[i]
__global__ void normalize_kernel(float* __restrict__ out, const float* __restrict__ denom) {
    int i = blockIdx.x * 256 + threadIdx.x;
    int row = i >> 7;
    float inv = 1.0f / denom[row];
    float4 v = ((const float4*)out)[i];
    v.x *= inv; v.y *= inv; v.z *= inv; v.w *= inv;
    ((float4*)out)[i] = v;
}

extern "C" void kernel_launch(void* const* d_in, const int* in_sizes, int n_in,
                              void* d_out, int out_size, void* d_ws, size_t ws_size,
                              hipStream_t stream) {
    const float* q     = (const float*)d_in[0];
    const float* hist  = (const float*)d_in[1];
    const float* times = (const float*)d_in[2];
    const float* w1    = (const float*)d_in[3];
    const float* b1    = (const float*)d_in[4];
    const float* w2    = (const float*)d_in[5];
    const float* b2    = (const float*)d_in[6];
    float* out = (float*)d_out;

    unsigned short* Qbf   = (unsigned short*)d_ws;        // 4 MB
    unsigned short* Kblk  = Qbf + (size_t)N * D;          // 4 MB
    unsigned short* Vblk  = Kblk + (size_t)N * D;         // 4 MB
    unsigned short* Opart = Vblk + (size_t)N * D;         // KS * 4 MB = 32 MB (bf16)
    float* dpart = (float*)(Opart + (size_t)KS * N * D);  // KS * 16 KB
    const size_t ws_needed = (size_t)(3 + KS) * N * D * 2 + (size_t)KS * N * 4;
    const int use_part = ws_size >= ws_needed;

    prep_all<<<2048 + NKT * 2, 256, 0, stream>>>(q, hist, Qbf, Kblk, Vblk);

    if (use_part) {
        flash_kernel<<<(N / BM) * KS, 512, 0, stream>>>(
            Qbf, Kblk, Vblk, times, w1, b1, w2, b2, Opart, dpart, out, 1);
        reduce_normalize_kernel<<<(N * D / 4) / 256, 256, 0, stream>>>(Opart, dpart, out);
    } else {
        float* denom = dpart;
        hipMemsetAsync(out, 0, (size_t)N * D * sizeof(float), stream);
        hipMemsetAsync(denom, 0, (size_t)N * sizeof(float), stream);
        flash_kernel<<<(N / BM) * KS, 512, 0, stream>>>(
            Qbf, Kblk, Vblk, times, w1, b1, w2, b2, Opart, denom, out, 0);
        normalize_kernel<<<(N * D / 4) / 256, 256, 0, stream>>>(out, denom);
    }
}

// Round 8
// 173.436 us; speedup vs baseline: 1.3363x; 1.3363x over previous
//
#include <hip/hip_runtime.h>

#define N 4096
#define D 512
#define FRAG_SH 512   // shorts per 16x32 MFMA fragment (1 KB)

typedef __attribute__((ext_vector_type(8))) short short8;
typedef __attribute__((ext_vector_type(4))) float f32x4;

__device__ __forceinline__ unsigned short f2bf(float f) {
    unsigned int u = __float_as_uint(f);
    u = (u + 0x7FFFu + ((u >> 16) & 1u)) >> 16;
    return (unsigned short)u;
}
__device__ __forceinline__ unsigned short f2bf_rn(float f) {
    return (unsigned short)((__float_as_uint(f) + 0x8000u) >> 16);
}
__device__ __forceinline__ void load_lds16(const unsigned short* g, unsigned short* l) {
    __builtin_amdgcn_global_load_lds(
        (const __attribute__((address_space(1))) void*)g,
        (__attribute__((address_space(3))) void*)l, 16, 0, 0);
}

// Prep: 256 blocks x 32 rows. Blocks [0,128): Q -> Qblk (A-frag-linear, scaled).
// Blocks [128,256): hist -> Kblk (B-frag-linear, d-major) + Vblk (B-frag, key-major).
// Frag content: lane ln holds X[fragrow*16 + (ln&15)][K32*32 + (ln>>4)*8 + j].
__global__ __launch_bounds__(256) void prep_kernel(const float* __restrict__ q,
                                                   const float* __restrict__ hist,
                                                   unsigned short* __restrict__ Qblk,
                                                   unsigned short* __restrict__ Kblk,
                                                   unsigned short* __restrict__ Vblk) {
    __shared__ unsigned short tile[32 * 512];
    const int bx = blockIdx.x;
    const int tid = threadIdx.x;
    const bool isQ = bx < 128;
    const int t = isQ ? bx : bx - 128;       // 32-row tile index
    const float* src = isQ ? q : hist;
    const float scale = isQ ? 0.04419417382415922f : 1.0f;   // 1/sqrt(512) into Q

    #pragma unroll
    for (int k = 0; k < 16; ++k) {
        int idx = tid + k * 256;
        int row = idx >> 7;
        int c4  = (idx & 127) << 2;
        float4 v = *(const float4*)(src + (size_t)(t * 32 + row) * D + c4);
        ushort4 o;
        o.x = f2bf(v.x * scale); o.y = f2bf(v.y * scale);
        o.z = f2bf(v.z * scale); o.w = f2bf(v.w * scale);
        *(ushort4*)(tile + row * 512 + c4) = o;
    }
    __syncthreads();

    // A/B-frag gather: frag index fl = dk*2 + rbl; dst frag = dk*256 + t*2 + rbl
    unsigned short* ABdst = isQ ? Qblk : Kblk;
    #pragma unroll
    for (int k = 0; k < 8; ++k) {
        int s = tid + k * 256;
        int fl = s >> 6, ln = s & 63;
        int dk = fl >> 1, rbl = fl & 1;
        int l16 = ln & 15, q4 = ln >> 4;
        short8 v = *(const short8*)(tile + (rbl * 16 + l16) * 512 + dk * 32 + q4 * 8);
        *(short8*)(ABdst + ((size_t)dk * 256 + t * 2 + rbl) * FRAG_SH + ln * 8) = v;
    }
    if (!isQ) {
        // Vblk frag (db, kb32=t): lane holds V[t*32 + q4*8 + j][db*16 + l16]
        #pragma unroll
        for (int k = 0; k < 8; ++k) {
            int s = tid + k * 256;
            int db = s >> 6, ln = s & 63;
            int l16 = ln & 15, q4 = ln >> 4;
            unsigned short tmp[8];
            #pragma unroll
            for (int j = 0; j < 8; ++j)
                tmp[j] = tile[(q4 * 8 + j) * 512 + db * 16 + l16];
            *(short8*)(Vblk + ((size_t)t * 32 + db) * FRAG_SH + ln * 8) = *(const short8*)tmp;
        }
    }
}

// K1: S-tile GEMM (128x128, BK=32, m97 recipe) + fused tw/exp epilogue.
// Writes P (bf16) in A-frag-linear layout (frag = kb32*256 + rb) and exp-row-sums
// into dsum via one atomic per row per wave. 1 barrier per K-iter.
__global__ __launch_bounds__(256, 3) void qk_kernel(
    const unsigned short* __restrict__ Qblk,
    const unsigned short* __restrict__ Kblk,
    const float* __restrict__ times,
    const float* __restrict__ w1, const float* __restrict__ b1,
    const float* __restrict__ w2, const float* __restrict__ b2,
    unsigned short* __restrict__ Pblk,
    float* __restrict__ dsum)
{
    __shared__ unsigned short smem[17408];   // union: 2x(A4096+B4096) dbuf | 4x4352 epi scratch

    const int tid  = threadIdx.x;
    const int wv   = tid >> 6;
    const int lane = tid & 63;
    const int q4   = lane >> 4;
    const int l16  = lane & 15;
    const int wy   = wv >> 1, wx = wv & 1;
    const int by   = blockIdx.y, bx = blockIdx.x;

    #define STAGE1(dk, b)                                                            \
        {                                                                            \
            _Pragma("unroll")                                                        \
            for (int i = 0; i < 2; ++i) {                                            \
                int sl = tid + i * 256;                                              \
                int f = sl >> 6, ln = sl & 63;                                       \
                load_lds16(Qblk + ((size_t)(dk) * 256 + by * 8 + f) * FRAG_SH + ln * 8, \
                           smem + (b) * 8192 + f * 512 + ln * 8);                    \
                load_lds16(Kblk + ((size_t)(dk) * 256 + bx * 8 + f) * FRAG_SH + ln * 8, \
                           smem + (b) * 8192 + 4096 + f * 512 + ln * 8);             \
            }                                                                        \
        }

    f32x4 acc[4][4];
    #pragma unroll
    for (int fy = 0; fy < 4; ++fy)
        #pragma unroll
        for (int fx = 0; fx < 4; ++fx) acc[fy][fx] = (f32x4){0.f, 0.f, 0.f, 0.f};

    STAGE1(0, 0);
    for (int dk = 0; dk < 16; ++dk) {
        __syncthreads();           // staging of buf (dk&1) complete; prior reads done
        const int b = dk & 1;
        if (dk < 15) STAGE1(dk + 1, b ^ 1);
        short8 a[4], bb[4];
        #pragma unroll
        for (int fy = 0; fy < 4; ++fy)
            a[fy] = *(const short8*)(smem + b * 8192 + (wy * 4 + fy) * 512 + lane * 8);
        #pragma unroll
        for (int fx = 0; fx < 4; ++fx)
            bb[fx] = *(const short8*)(smem + b * 8192 + 4096 + (wx * 4 + fx) * 512 + lane * 8);
        #pragma unroll
        for (int fy = 0; fy < 4; ++fy)
            #pragma unroll
            for (int fx = 0; fx < 4; ++fx)
                acc[fy][fx] = __builtin_amdgcn_mfma_f32_16x16x32_bf16(a[fy], bb[fx], acc[fy][fx], 0, 0, 0);
    }
    __syncthreads();   // staging buffers free -> reuse as epilogue scratch
    #undef STAGE1

    // ---- epilogue: tw * exp, row-sum atomics, C->A transform via wave scratch ----
    float w1v[8], b1v[8], w2v[8];
    #pragma unroll
    for (int k = 0; k < 8; ++k) { w1v[k] = w1[k]; b1v[k] = b1[k]; w2v[k] = w2[k]; }
    const float b2v = b2[0];
    bool fast = true;
    #pragma unroll
    for (int k = 0; k < 8; ++k) fast = fast && (b1v[k] == 0.0f);
    float C1 = 0.0f;
    #pragma unroll
    for (int k = 0; k < 8; ++k) C1 += w2v[k] * fmaxf(w1v[k], 0.0f);

    const int rowbase = by * 128 + wy * 64;
    const int colbase = bx * 128 + wx * 64;
    float tcol[4];
    #pragma unroll
    for (int fx = 0; fx < 4; ++fx) tcol[fx] = times[colbase + fx * 16 + l16];

    unsigned short* sc = smem + wv * 4352;    // wave-private 64 x 68 bf16
    #pragma unroll
    for (int fy = 0; fy < 4; ++fy) {
        #pragma unroll
        for (int ri = 0; ri < 4; ++ri) {
            const float tq = times[rowbase + fy * 16 + q4 * 4 + ri];
            float se = 0.f;
            #pragma unroll
            for (int fx = 0; fx < 4; ++fx) {
                float td = fabsf(tq - tcol[fx]);
                float a = fmaf(td, C1, b2v);
                if (!fast) {
                    a = b2v;
                    #pragma unroll
                    for (int k = 0; k < 8; ++k)
                        a += w2v[k] * fmaxf(fmaf(td, w1v[k], b1v[k]), 0.f);
                }
                float twt = __builtin_amdgcn_rcpf(1.0f + __expf(-a));
                float e = __expf(acc[fy][fx][ri] * twt);
                se += e;
                sc[(fy * 16 + q4 * 4 + ri) * 68 + fx * 16 + l16] = f2bf_rn(e);
            }
            se += __shfl_xor(se, 1);
            se += __shfl_xor(se, 2);
            se += __shfl_xor(se, 4);
            se += __shfl_xor(se, 8);
            if (l16 == 0) atomicAdd(dsum + rowbase + fy * 16 + q4 * 4 + ri, se);
        }
    }
    // read back A-frags (wave-synchronous LDS, no barrier needed) -> global Pblk
    #pragma unroll
    for (int rbl = 0; rbl < 4; ++rbl)
        #pragma unroll
        for (int kb = 0; kb < 2; ++kb) {
            short8 v = *(const short8*)(sc + (rbl * 16 + l16) * 68 + kb * 32 + q4 * 8);
            size_t fidx = (size_t)(bx * 4 + wx * 2 + kb) * 256 + (by * 8 + wy * 4 + rbl);
            *(short8*)(Pblk + fidx * FRAG_SH + lane * 8) = v;
        }
}

// K2: O-partial GEMM (128 rows x 64 dcols, BK=32 keys, split-K over gridDim.z).
// A = Pblk (frag-linear), B = Vblk (frag-linear); m97 staging, 1 barrier/iter.
__global__ __launch_bounds__(256, 3) void pv_kernel(
    const unsigned short* __restrict__ Pblk,
    const unsigned short* __restrict__ Vblk,
    unsigned short* __restrict__ Opart,   // bf16 [nchunk][N][D]
    int iters)
{
    __shared__ unsigned short smem[12288];   // 2 x (A 4096 + B 2048) shorts = 24 KB

    const int tid  = threadIdx.x;
    const int wv   = tid >> 6;
    const int lane = tid & 63;
    const int q4   = lane >> 4;
    const int l16  = lane & 15;
    const int wy   = wv >> 1, wx = wv & 1;
    const int bx   = blockIdx.x;      // 0..7 d-tile (64 cols)
    const int by   = blockIdx.y;      // 0..31 m-tile (128 rows)
    const int chunk = blockIdx.z;
    const int kbase = chunk * iters;  // in kb32 units

    #define STAGE2(it, b)                                                            \
        {                                                                            \
            const int kb32 = kbase + (it);                                           \
            _Pragma("unroll")                                                        \
            for (int j = 0; j < 3; ++j) {                                            \
                int sl = tid + j * 256;                                              \
                if (sl < 512) {                                                      \
                    int f = sl >> 6, ln = sl & 63;                                   \
                    load_lds16(Pblk + ((size_t)kb32 * 256 + by * 8 + f) * FRAG_SH + ln * 8, \
                               smem + (b) * 6144 + f * 512 + ln * 8);                \
                } else {                                                             \
                    int s2 = sl - 512;                                               \
                    int f = s2 >> 6, ln = s2 & 63;                                   \
                    load_lds16(Vblk + ((size_t)kb32 * 32 + bx * 4 + f) * FRAG_SH + ln * 8, \
                               smem + (b) * 6144 + 4096 + f * 512 + ln * 8);         \
                }                                                                    \
            }                                                                        \
        }

    f32x4 acc[4][2];
    #pragma unroll
    for (int fy = 0; fy < 4; ++fy)
        #pragma unroll
        for (int fx = 0; fx < 2; ++fx) acc[fy][fx] = (f32x4){0.f, 0.f, 0.f, 0.f};

    STAGE2(0, 0);
    for (int it = 0; it < iters; ++it) {
        __syncthreads();
        const int b = it & 1;
        if (it + 1 < iters) STAGE2(it + 1, b ^ 1);
        short8 a[4], vv[2];
        #pragma unroll
        for (int fy = 0; fy < 4; ++fy)
            a[fy] = *(const short8*)(smem + b * 6144 + (wy * 4 + fy) * 512 + lane * 8);
        #pragma unroll
        for (int fx = 0; fx < 2; ++fx)
            vv[fx] = *(const short8*)(smem + b * 6144 + 4096 + (wx * 2 + fx) * 512 + lane * 8);
        #pragma unroll
        for (int fy = 0; fy < 4; ++fy)
            #pragma unroll
            for (int fx = 0; fx < 2; ++fx)
                acc[fy][fx] = __builtin_amdgcn_mfma_f32_16x16x32_bf16(a[fy], vv[fx], acc[fy][fx], 0, 0, 0);
    }
    #undef STAGE2

    unsigned short* ob = Opart + (size_t)chunk * N * D;
    #pragma unroll
    for (int fy = 0; fy < 4; ++fy)
        #pragma unroll
        for (int ri = 0; ri < 4; ++ri) {
            const int row = by * 128 + wy * 64 + fy * 16 + q4 * 4 + ri;
            #pragma unroll
            for (int fx = 0; fx < 2; ++fx) {
                const int col = bx * 64 + wx * 32 + fx * 16 + l16;
                ob[(size_t)row * D + col] = f2bf_rn(acc[fy][fx][ri]);
            }
        }
}

// out[i,:] = (sum_c Opart[c][i,:]) / dsum[i]
__global__ void reduce_normalize_kernel(const unsigned short* __restrict__ Opart,
                                        const float* __restrict__ dsum,
                                        float* __restrict__ out, int nchunk) {
    int i = blockIdx.x * 256 + threadIdx.x;   // ushort4/float4 index
    int row = i >> 7;
    float inv = 1.0f / dsum[row];
    float4 acc = {0.f, 0.f, 0.f, 0.f};
    for (int c = 0; c < nchunk; ++c) {
        ushort4 u = ((const ushort4*)(Opart + (size_t)c * N * D))[i];
        acc.x += __uint_as_float((unsigned)u.x << 16);
        acc.y += __uint_as_float((unsigned)u.y << 16);
        acc.z += __uint_as_float((unsigned)u.z << 16);
        acc.w += __uint_as_float((unsigned)u.w << 16);
    }
    acc.x *= inv; acc.y *= inv; acc.z *= inv; acc.w *= inv;
    ((float4*)out)[i] = acc;
}

extern "C" void kernel_launch(void* const* d_in, const int* in_sizes, int n_in,
                              void* d_out, int out_size, void* d_ws, size_t ws_size,
                              hipStream_t stream) {
    const float* q     = (const float*)d_in[0];
    const float* hist  = (const float*)d_in[1];
    const float* times = (const float*)d_in[2];
    const float* w1    = (const float*)d_in[3];
    const float* b1    = (const float*)d_in[4];
    const float* w2    = (const float*)d_in[5];
    const float* b2    = (const float*)d_in[6];
    float* out = (float*)d_out;

    // ws layout (bytes):
    //   [0, 4M)        Vblk        (K2 reads)
    //   [4M, 36M)      Pblk        (K1 writes, K2 reads; L3-resident)
    //   [36M, +64K)    dsum
    //   [.., +4M)      Qblk        (K1 only)
    //   [.., +4M)      Kblk        (K1 only)
    //   Opart = starts at Qblk (aliases Qblk/Kblk; K2/reduce never touch them)
    char* base = (char*)d_ws;
    const size_t MB4 = (size_t)N * D * 2;              // 4 MiB
    unsigned short* Vblk = (unsigned short*)base;
    unsigned short* Pblk = (unsigned short*)(base + MB4);
    float* dsum          = (float*)(base + MB4 + (size_t)N * (size_t)N * 2);
    char* qb_base        = base + MB4 + (size_t)N * (size_t)N * 2 + 65536;
    unsigned short* Qblk = (unsigned short*)qb_base;
    unsigned short* Kblk = (unsigned short*)(qb_base + MB4);
    unsigned short* Opart = (unsigned short*)qb_base;  // aliases Qblk/Kblk

    const size_t fixed = (size_t)(qb_base - base);
    const int KS2 = (ws_size >= fixed + 4 * MB4) ? 4 : 2;   // Opart = KS2 * 4 MiB
    const int iters = (N / 32) / KS2;

    hipMemsetAsync(dsum, 0, (size_t)N * sizeof(float), stream);
    prep_kernel<<<256, 256, 0, stream>>>(q, hist, Qblk, Kblk, Vblk);
    qk_kernel<<<dim3(32, 32), 256, 0, stream>>>(Qblk, Kblk, times, w1, b1, w2, b2, Pblk, dsum);
    pv_kernel<<<dim3(8, 32, KS2), 256, 0, stream>>>(Pblk, Vblk, Opart, iters);
    reduce_normalize_kernel<<<(N * D / 4) / 256, 256, 0, stream>>>(Opart, dsum, out, KS2);
}

// Round 9
// 166.500 us; speedup vs baseline: 1.3919x; 1.0417x over previous
//
#include <hip/hip_runtime.h>

#define N 4096
#define D 512
#define FRAG_SH 512   // shorts per 16x32 MFMA fragment (1 KB)

typedef __attribute__((ext_vector_type(8))) short short8;
typedef __attribute__((ext_vector_type(4))) float f32x4;

__device__ __forceinline__ unsigned short f2bf(float f) {
    unsigned int u = __float_as_uint(f);
    u = (u + 0x7FFFu + ((u >> 16) & 1u)) >> 16;
    return (unsigned short)u;
}
__device__ __forceinline__ unsigned short f2bf_rn(float f) {
    return (unsigned short)((__float_as_uint(f) + 0x8000u) >> 16);
}

// Prep: 256 blocks x 32 rows. Blocks [0,128): Q -> Qblk (A-frag-linear, scaled).
// Blocks [128,256): hist -> Kblk (B-frag-linear, d-major) + Vblk (B-frag, key-major).
// Frag content: lane ln holds X[fragrow*16 + (ln&15)][K32*32 + (ln>>4)*8 + j].
__global__ __launch_bounds__(256) void prep_kernel(const float* __restrict__ q,
                                                   const float* __restrict__ hist,
                                                   unsigned short* __restrict__ Qblk,
                                                   unsigned short* __restrict__ Kblk,
                                                   unsigned short* __restrict__ Vblk) {
    __shared__ unsigned short tile[32 * 512];
    const int bx = blockIdx.x;
    const int tid = threadIdx.x;
    const bool isQ = bx < 128;
    const int t = isQ ? bx : bx - 128;       // 32-row tile index
    const float* src = isQ ? q : hist;
    const float scale = isQ ? 0.04419417382415922f : 1.0f;   // 1/sqrt(512) into Q

    #pragma unroll
    for (int k = 0; k < 16; ++k) {
        int idx = tid + k * 256;
        int row = idx >> 7;
        int c4  = (idx & 127) << 2;
        float4 v = *(const float4*)(src + (size_t)(t * 32 + row) * D + c4);
        ushort4 o;
        o.x = f2bf(v.x * scale); o.y = f2bf(v.y * scale);
        o.z = f2bf(v.z * scale); o.w = f2bf(v.w * scale);
        *(ushort4*)(tile + row * 512 + c4) = o;
    }
    __syncthreads();

    unsigned short* ABdst = isQ ? Qblk : Kblk;
    #pragma unroll
    for (int k = 0; k < 8; ++k) {
        int s = tid + k * 256;
        int fl = s >> 6, ln = s & 63;
        int dk = fl >> 1, rbl = fl & 1;
        int l16 = ln & 15, q4 = ln >> 4;
        short8 v = *(const short8*)(tile + (rbl * 16 + l16) * 512 + dk * 32 + q4 * 8);
        *(short8*)(ABdst + ((size_t)dk * 256 + t * 2 + rbl) * FRAG_SH + ln * 8) = v;
    }
    if (!isQ) {
        #pragma unroll
        for (int k = 0; k < 8; ++k) {
            int s = tid + k * 256;
            int db = s >> 6, ln = s & 63;
            int l16 = ln & 15, q4 = ln >> 4;
            unsigned short tmp[8];
            #pragma unroll
            for (int j = 0; j < 8; ++j)
                tmp[j] = tile[(q4 * 8 + j) * 512 + db * 16 + l16];
            *(short8*)(Vblk + ((size_t)t * 32 + db) * FRAG_SH + ln * 8) = *(const short8*)tmp;
        }
    }
}

// K1: S-tile GEMM, barrier-free. Block = 64 qrows x 256 keys, 4 waves (one per
// 64-key strip). All MFMA A/B frags read DIRECTLY from frag-linear global
// (coalesced dwordx4, L2/L3-hot) -> compiler pipelines with per-load vmcnt;
// no LDS staging, zero __syncthreads. LDS = wave-private epilogue scratch only.
__global__ __launch_bounds__(256, 3) void qk_kernel(
    const unsigned short* __restrict__ Qblk,
    const unsigned short* __restrict__ Kblk,
    const float* __restrict__ times,
    const float* __restrict__ w1, const float* __restrict__ b1,
    const float* __restrict__ w2, const float* __restrict__ b2,
    unsigned short* __restrict__ Pblk,
    float* __restrict__ dsum)
{
    __shared__ unsigned short sc_all[4][64 * 68];   // 34.8 KB, wave-private scratch

    const int tid  = threadIdx.x;
    const int wv   = tid >> 6;
    const int lane = tid & 63;
    const int q4   = lane >> 4;
    const int l16  = lane & 15;
    const int b    = blockIdx.x;                    // 1024 blocks
    // XCD-affine swizzle: col-group pinned per XCD (K-slice 512 KB L2-resident)
    const int cg = ((b & 7) << 1) | ((b >> 3) & 1); // 0..15: 256-key group
    const int rg = b >> 4;                          // 0..63: 64-row group
    const int wx = wv;                              // 64-key strip within group

    f32x4 acc[4][4];
    #pragma unroll
    for (int fy = 0; fy < 4; ++fy)
        #pragma unroll
        for (int fx = 0; fx < 4; ++fx) acc[fy][fx] = (f32x4){0.f, 0.f, 0.f, 0.f};

    // ---- K-loop: 16 iters, no barriers, frags straight from global ----
    for (int dk = 0; dk < 16; ++dk) {
        short8 a[4], bb[4];
        #pragma unroll
        for (int fy = 0; fy < 4; ++fy)
            a[fy] = *(const short8*)(Qblk + ((size_t)dk * 256 + rg * 4 + fy) * FRAG_SH + lane * 8);
        #pragma unroll
        for (int fx = 0; fx < 4; ++fx)
            bb[fx] = *(const short8*)(Kblk + ((size_t)dk * 256 + cg * 16 + wx * 4 + fx) * FRAG_SH + lane * 8);
        #pragma unroll
        for (int fy = 0; fy < 4; ++fy)
            #pragma unroll
            for (int fx = 0; fx < 4; ++fx)
                acc[fy][fx] = __builtin_amdgcn_mfma_f32_16x16x32_bf16(a[fy], bb[fx], acc[fy][fx], 0, 0, 0);
    }

    // ---- epilogue: tw * exp, row-sum atomics, C->A transform (wave-sync LDS) ----
    float w1v[8], b1v[8], w2v[8];
    #pragma unroll
    for (int k = 0; k < 8; ++k) { w1v[k] = w1[k]; b1v[k] = b1[k]; w2v[k] = w2[k]; }
    const float b2v = b2[0];
    bool fast = true;
    #pragma unroll
    for (int k = 0; k < 8; ++k) fast = fast && (b1v[k] == 0.0f);
    float C1 = 0.0f;
    #pragma unroll
    for (int k = 0; k < 8; ++k) C1 += w2v[k] * fmaxf(w1v[k], 0.0f);

    const int rowbase = rg * 64;
    const int colbase = cg * 256 + wx * 64;
    float tcol[4];
    #pragma unroll
    for (int fx = 0; fx < 4; ++fx) tcol[fx] = times[colbase + fx * 16 + l16];

    unsigned short* sc = sc_all[wv];   // 64 x 68 bf16
    #pragma unroll
    for (int fy = 0; fy < 4; ++fy) {
        #pragma unroll
        for (int ri = 0; ri < 4; ++ri) {
            const float tq = times[rowbase + fy * 16 + q4 * 4 + ri];
            float se = 0.f;
            #pragma unroll
            for (int fx = 0; fx < 4; ++fx) {
                float td = fabsf(tq - tcol[fx]);
                float a = fmaf(td, C1, b2v);
                if (!fast) {
                    a = b2v;
                    #pragma unroll
                    for (int k = 0; k < 8; ++k)
                        a += w2v[k] * fmaxf(fmaf(td, w1v[k], b1v[k]), 0.f);
                }
                float twt = __builtin_amdgcn_rcpf(1.0f + __expf(-a));
                float e = __expf(acc[fy][fx][ri] * twt);
                se += e;
                sc[(fy * 16 + q4 * 4 + ri) * 68 + fx * 16 + l16] = f2bf_rn(e);
            }
            se += __shfl_xor(se, 1);
            se += __shfl_xor(se, 2);
            se += __shfl_xor(se, 4);
            se += __shfl_xor(se, 8);
            if (l16 == 0) atomicAdd(dsum + rowbase + fy * 16 + q4 * 4 + ri, se);
        }
    }
    // read back A-frags (wave-synchronous LDS) -> global Pblk (frag-linear)
    #pragma unroll
    for (int fy = 0; fy < 4; ++fy)
        #pragma unroll
        for (int kb = 0; kb < 2; ++kb) {
            short8 v = *(const short8*)(sc + (fy * 16 + l16) * 68 + kb * 32 + q4 * 8);
            size_t fidx = (size_t)(cg * 8 + wx * 2 + kb) * 256 + (rg * 4 + fy);
            *(short8*)(Pblk + fidx * FRAG_SH + lane * 8) = v;
        }
}

// K2: O-partial GEMM, barrier-free, no LDS. Block = 64 rows x 256 dcols,
// 4 waves (one per 64-col strip), split-K over gridDim.z. A (Pblk) and
// B (Vblk) frags straight from frag-linear global (L2/L3-hot).
__global__ __launch_bounds__(256, 3) void pv_kernel(
    const unsigned short* __restrict__ Pblk,
    const unsigned short* __restrict__ Vblk,
    unsigned short* __restrict__ Opart,   // bf16 [nchunk][N][D]
    int iters)
{
    const int tid  = threadIdx.x;
    const int wv   = tid >> 6;
    const int lane = tid & 63;
    const int q4   = lane >> 4;
    const int l16  = lane & 15;
    const int cgz  = blockIdx.x;      // 0..1: 256-col group
    const int rg   = blockIdx.y;      // 0..63: 64-row group
    const int chunk = blockIdx.z;
    const int wx   = wv;              // 64-col strip
    const int kbase = chunk * iters;  // kb32 units

    f32x4 acc[4][4];
    #pragma unroll
    for (int fy = 0; fy < 4; ++fy)
        #pragma unroll
        for (int fx = 0; fx < 4; ++fx) acc[fy][fx] = (f32x4){0.f, 0.f, 0.f, 0.f};

    for (int it = 0; it < iters; ++it) {
        const int kb32 = kbase + it;
        short8 a[4], vv[4];
        #pragma unroll
        for (int fy = 0; fy < 4; ++fy)
            a[fy] = *(const short8*)(Pblk + ((size_t)kb32 * 256 + rg * 4 + fy) * FRAG_SH + lane * 8);
        #pragma unroll
        for (int fx = 0; fx < 4; ++fx)
            vv[fx] = *(const short8*)(Vblk + ((size_t)kb32 * 32 + cgz * 16 + wx * 4 + fx) * FRAG_SH + lane * 8);
        #pragma unroll
        for (int fy = 0; fy < 4; ++fy)
            #pragma unroll
            for (int fx = 0; fx < 4; ++fx)
                acc[fy][fx] = __builtin_amdgcn_mfma_f32_16x16x32_bf16(a[fy], vv[fx], acc[fy][fx], 0, 0, 0);
    }

    unsigned short* ob = Opart + (size_t)chunk * N * D;
    #pragma unroll
    for (int fy = 0; fy < 4; ++fy)
        #pragma unroll
        for (int ri = 0; ri < 4; ++ri) {
            const int row = rg * 64 + fy * 16 + q4 * 4 + ri;
            #pragma unroll
            for (int fx = 0; fx < 4; ++fx) {
                const int col = cgz * 256 + wx * 64 + fx * 16 + l16;
                ob[(size_t)row * D + col] = f2bf_rn(acc[fy][fx][ri]);
            }
        }
}

// out[i,:] = (sum_c Opart[c][i,:]) / dsum[i]
__global__ void reduce_normalize_kernel(const unsigned short* __restrict__ Opart,
                                        const float* __restrict__ dsum,
                                        float* __restrict__ out, int nchunk) {
    int i = blockIdx.x * 256 + threadIdx.x;   // ushort4/float4 index
    int row = i >> 7;
    float inv = 1.0f / dsum[row];
    float4 acc = {0.f, 0.f, 0.f, 0.f};
    for (int c = 0; c < nchunk; ++c) {
        ushort4 u = ((const ushort4*)(Opart + (size_t)c * N * D))[i];
        acc.x += __uint_as_float((unsigned)u.x << 16);
        acc.y += __uint_as_float((unsigned)u.y << 16);
        acc.z += __uint_as_float((unsigned)u.z << 16);
        acc.w += __uint_as_float((unsigned)u.w << 16);
    }
    acc.x *= inv; acc.y *= inv; acc.z *= inv; acc.w *= inv;
    ((float4*)out)[i] = acc;
}

extern "C" void kernel_launch(void* const* d_in, const int* in_sizes, int n_in,
                              void* d_out, int out_size, void* d_ws, size_t ws_size,
                              hipStream_t stream) {
    const float* q     = (const float*)d_in[0];
    const float* hist  = (const float*)d_in[1];
    const float* times = (const float*)d_in[2];
    const float* w1    = (const float*)d_in[3];
    const float* b1    = (const float*)d_in[4];
    const float* w2    = (const float*)d_in[5];
    const float* b2    = (const float*)d_in[6];
    float* out = (float*)d_out;

    // ws layout: Vblk 4M | Pblk 32M | dsum 64K | Qblk 4M | Kblk 4M
    // Opart aliases Qblk/Kblk (pv/reduce never touch them).
    char* base = (char*)d_ws;
    const size_t MB4 = (size_t)N * D * 2;              // 4 MiB
    unsigned short* Vblk = (unsigned short*)base;
    unsigned short* Pblk = (unsigned short*)(base + MB4);
    float* dsum          = (float*)(base + MB4 + (size_t)N * (size_t)N * 2);
    char* qb_base        = base + MB4 + (size_t)N * (size_t)N * 2 + 65536;
    unsigned short* Qblk = (unsigned short*)qb_base;
    unsigned short* Kblk = (unsigned short*)(qb_base + MB4);
    unsigned short* Opart = (unsigned short*)qb_base;  // aliases Qblk/Kblk

    const size_t fixed = (size_t)(qb_base - base);
    const int KS2 = (ws_size >= fixed + 4 * MB4) ? 4 : 2;   // Opart = KS2 * 4 MiB
    const int iters = (N / 32) / KS2;

    hipMemsetAsync(dsum, 0, (size_t)N * sizeof(float), stream);
    prep_kernel<<<256, 256, 0, stream>>>(q, hist, Qblk, Kblk, Vblk);
    qk_kernel<<<1024, 256, 0, stream>>>(Qblk, Kblk, times, w1, b1, w2, b2, Pblk, dsum);
    pv_kernel<<<dim3(2, 64, KS2), 256, 0, stream>>>(Pblk, Vblk, Opart, iters);
    reduce_normalize_kernel<<<(N * D / 4) / 256, 256, 0, stream>>>(Opart, dsum, out, KS2);
}

// Round 10
// 150.622 us; speedup vs baseline: 1.5387x; 1.1054x over previous
//
#include <hip/hip_runtime.h>
#include <hip/hip_cooperative_groups.h>

namespace cg = cooperative_groups;

#define N 4096
#define D 512
#define FRAG_SH 512            // shorts per 16x32 MFMA fragment (1 KB)
#define NBLK 512
#define NTHR 256
#define SC_STRIDE 136          // sc row stride in shorts (272 B, 16B-aligned)
#define SMEM_BYTES 69632       // 4 waves * 64 rows * 136 shorts * 2 B

typedef __attribute__((ext_vector_type(8))) short short8;
typedef __attribute__((ext_vector_type(4))) float f32x4;

__device__ __forceinline__ unsigned short f2bf(float f) {
    unsigned int u = __float_as_uint(f);
    u = (u + 0x7FFFu + ((u >> 16) & 1u)) >> 16;
    return (unsigned short)u;
}
__device__ __forceinline__ unsigned short f2bf_rn(float f) {
    return (unsigned short)((__float_as_uint(f) + 0x8000u) >> 16);
}
__device__ __forceinline__ float bf2f(unsigned short u) {
    return __uint_as_float((unsigned)u << 16);
}

// ---------------- phase: prep ----------------
// blocks [0,128): Q 32-row tile -> Qblk (A-frag-linear, pre-scaled 1/sqrt(D))
// blocks [128,256): hist 32-row tile -> Kblk (B-frag) + Vblk (B-frag)
// blocks [256,258): zero dsum
__device__ __forceinline__ void prep_phase(int bid, int tid,
    const float* __restrict__ q, const float* __restrict__ hist,
    unsigned short* __restrict__ Qblk, unsigned short* __restrict__ Kblk,
    unsigned short* __restrict__ Vblk, float* __restrict__ dsum)
{
    extern __shared__ unsigned short smem[];
    if (bid >= 256) {
        if (bid < 258) {
            int z = (bid - 256) * NTHR + tid;       // 0..511
            #pragma unroll
            for (int j = 0; j < 8; ++j) dsum[z * 8 + j] = 0.f;
        }
        return;
    }
    const bool isQ = bid < 128;
    const int t = isQ ? bid : bid - 128;            // 32-row tile
    const float* src = isQ ? q : hist;
    const float scale = isQ ? 0.04419417382415922f : 1.0f;

    #pragma unroll
    for (int k = 0; k < 16; ++k) {
        int idx = tid + k * 256;
        int row = idx >> 7;
        int c4  = (idx & 127) << 2;
        float4 v = *(const float4*)(src + (size_t)(t * 32 + row) * D + c4);
        ushort4 o;
        o.x = f2bf(v.x * scale); o.y = f2bf(v.y * scale);
        o.z = f2bf(v.z * scale); o.w = f2bf(v.w * scale);
        *(ushort4*)(smem + row * 512 + c4) = o;
    }
    __syncthreads();

    unsigned short* ABdst = isQ ? Qblk : Kblk;
    #pragma unroll
    for (int k = 0; k < 8; ++k) {
        int s = tid + k * 256;
        int fl = s >> 6, ln = s & 63;
        int dk = fl >> 1, rbl = fl & 1;
        int l16 = ln & 15, qq = ln >> 4;
        short8 v = *(const short8*)(smem + (rbl * 16 + l16) * 512 + dk * 32 + qq * 8);
        *(short8*)(ABdst + ((size_t)dk * 256 + t * 2 + rbl) * FRAG_SH + ln * 8) = v;
    }
    if (!isQ) {
        #pragma unroll
        for (int k = 0; k < 8; ++k) {
            int s = tid + k * 256;
            int db = s >> 6, ln = s & 63;
            int l16 = ln & 15, qq = ln >> 4;
            unsigned short tmp[8];
            #pragma unroll
            for (int j = 0; j < 8; ++j)
                tmp[j] = smem[(qq * 8 + j) * 512 + db * 16 + l16];
            *(short8*)(Vblk + ((size_t)t * 32 + db) * FRAG_SH + ln * 8) = *(const short8*)tmp;
        }
    }
}

// ---------------- phase: qk ----------------
// 512 blocks: rg = bid>>4 (128-row group), cg = bid&15 (256-col group).
// 4 waves, wave tile 64x128 (acc 4x8): 32 MFMA + 12 coalesced 1KB loads per iter.
// Epilogue: collapsed-MLP tw * exp, row-sum atomics, C->A transform via
// wave-private LDS, P written frag-linear.
__device__ __forceinline__ void qk_phase(int bid, int tid,
    const unsigned short* __restrict__ Qblk, const unsigned short* __restrict__ Kblk,
    const float* __restrict__ times,
    const float* __restrict__ w1, const float* __restrict__ b1,
    const float* __restrict__ w2, const float* __restrict__ b2,
    unsigned short* __restrict__ Pblk, float* __restrict__ dsum)
{
    extern __shared__ unsigned short smem[];
    const int wv = tid >> 6, lane = tid & 63;
    const int qq = lane >> 4, l16 = lane & 15;
    const int wy = wv >> 1, wx = wv & 1;
    const int rg = bid >> 4;
    const int cg = bid & 15;

    f32x4 acc[4][8];
    #pragma unroll
    for (int fy = 0; fy < 4; ++fy)
        #pragma unroll
        for (int fx = 0; fx < 8; ++fx) acc[fy][fx] = (f32x4){0.f, 0.f, 0.f, 0.f};

    for (int dk = 0; dk < 16; ++dk) {
        short8 a[4], b[8];
        #pragma unroll
        for (int fy = 0; fy < 4; ++fy)
            a[fy] = *(const short8*)(Qblk + ((size_t)dk * 256 + rg * 8 + wy * 4 + fy) * FRAG_SH + lane * 8);
        #pragma unroll
        for (int fx = 0; fx < 8; ++fx)
            b[fx] = *(const short8*)(Kblk + ((size_t)dk * 256 + cg * 16 + wx * 8 + fx) * FRAG_SH + lane * 8);
        #pragma unroll
        for (int fy = 0; fy < 4; ++fy)
            #pragma unroll
            for (int fx = 0; fx < 8; ++fx)
                acc[fy][fx] = __builtin_amdgcn_mfma_f32_16x16x32_bf16(a[fy], b[fx], acc[fy][fx], 0, 0, 0);
    }

    float w1v[8], b1v[8], w2v[8];
    #pragma unroll
    for (int k = 0; k < 8; ++k) { w1v[k] = w1[k]; b1v[k] = b1[k]; w2v[k] = w2[k]; }
    const float b2v = b2[0];
    bool fast = true;
    #pragma unroll
    for (int k = 0; k < 8; ++k) fast = fast && (b1v[k] == 0.0f);
    float C1 = 0.0f;
    #pragma unroll
    for (int k = 0; k < 8; ++k) C1 += w2v[k] * fmaxf(w1v[k], 0.0f);

    const int rowbase = rg * 128 + wy * 64;
    const int colbase = cg * 256 + wx * 128;
    float tcol[8];
    #pragma unroll
    for (int fx = 0; fx < 8; ++fx) tcol[fx] = times[colbase + fx * 16 + l16];

    unsigned short* sc = smem + wv * (64 * SC_STRIDE);   // wave-private 64x136
    #pragma unroll
    for (int fy = 0; fy < 4; ++fy) {
        #pragma unroll
        for (int ri = 0; ri < 4; ++ri) {
            const float tq = times[rowbase + fy * 16 + qq * 4 + ri];
            float se = 0.f;
            #pragma unroll
            for (int fx = 0; fx < 8; ++fx) {
                float td = fabsf(tq - tcol[fx]);
                float a = fmaf(td, C1, b2v);
                if (!fast) {
                    a = b2v;
                    #pragma unroll
                    for (int k = 0; k < 8; ++k)
                        a += w2v[k] * fmaxf(fmaf(td, w1v[k], b1v[k]), 0.f);
                }
                float twt = __builtin_amdgcn_rcpf(1.0f + __expf(-a));
                float e = __expf(acc[fy][fx][ri] * twt);   // 1/sqrt(D) folded into Q
                se += e;
                sc[(fy * 16 + qq * 4 + ri) * SC_STRIDE + fx * 16 + l16] = f2bf_rn(e);
            }
            se += __shfl_xor(se, 1);
            se += __shfl_xor(se, 2);
            se += __shfl_xor(se, 4);
            se += __shfl_xor(se, 8);
            if (l16 == 0) atomicAdd(dsum + rowbase + fy * 16 + qq * 4 + ri, se);
        }
    }
    // readback A-frags (wave-synchronous LDS) -> frag-linear Pblk
    #pragma unroll
    for (int fy = 0; fy < 4; ++fy)
        #pragma unroll
        for (int kb = 0; kb < 4; ++kb) {
            short8 v = *(const short8*)(sc + (fy * 16 + l16) * SC_STRIDE + kb * 32 + qq * 8);
            size_t fidx = (size_t)(cg * 8 + wx * 4 + kb) * 256 + (rg * 8 + wy * 4 + fy);
            *(short8*)(Pblk + fidx * FRAG_SH + lane * 8) = v;
        }
}

// ---------------- phase: pv ----------------
// units = 32 rg x 2 cgp x KS2 chunks; block tile 128r x 256c, wave 64x128.
__device__ __forceinline__ void pv_phase(int bid, int tid,
    const unsigned short* __restrict__ Pblk, const unsigned short* __restrict__ Vblk,
    unsigned short* __restrict__ Opart, int KS2)
{
    const int wv = tid >> 6, lane = tid & 63;
    const int qq = lane >> 4, l16 = lane & 15;
    const int wy = wv >> 1, wx = wv & 1;
    const int iters = (N / 32) / KS2;
    const int units = 64 * KS2;

    for (int u = bid; u < units; u += NBLK) {
        const int chunk = u % KS2;
        const int v2 = u / KS2;
        const int cgp = v2 & 1;
        const int rg  = v2 >> 1;
        const int kbase = chunk * iters;

        f32x4 acc[4][8];
        #pragma unroll
        for (int fy = 0; fy < 4; ++fy)
            #pragma unroll
            for (int fx = 0; fx < 8; ++fx) acc[fy][fx] = (f32x4){0.f, 0.f, 0.f, 0.f};

        for (int it = 0; it < iters; ++it) {
            const int kb32 = kbase + it;
            short8 a[4], b[8];
            #pragma unroll
            for (int fy = 0; fy < 4; ++fy)
                a[fy] = *(const short8*)(Pblk + ((size_t)kb32 * 256 + rg * 8 + wy * 4 + fy) * FRAG_SH + lane * 8);
            #pragma unroll
            for (int fx = 0; fx < 8; ++fx)
                b[fx] = *(const short8*)(Vblk + ((size_t)kb32 * 32 + cgp * 16 + wx * 8 + fx) * FRAG_SH + lane * 8);
            #pragma unroll
            for (int fy = 0; fy < 4; ++fy)
                #pragma unroll
                for (int fx = 0; fx < 8; ++fx)
                    acc[fy][fx] = __builtin_amdgcn_mfma_f32_16x16x32_bf16(a[fy], b[fx], acc[fy][fx], 0, 0, 0);
        }

        unsigned short* ob = Opart + (size_t)chunk * N * D;
        #pragma unroll
        for (int fy = 0; fy < 4; ++fy)
            #pragma unroll
            for (int ri = 0; ri < 4; ++ri) {
                const int row = rg * 128 + wy * 64 + fy * 16 + qq * 4 + ri;
                #pragma unroll
                for (int fx = 0; fx < 8; ++fx) {
                    const int col = cgp * 256 + wx * 128 + fx * 16 + l16;
                    ob[(size_t)row * D + col] = f2bf_rn(acc[fy][fx][ri]);
                }
            }
    }
}

// ---------------- phase: reduce ----------------
__device__ __forceinline__ void reduce_phase(int bid, int tid,
    const unsigned short* __restrict__ Opart, const float* __restrict__ dsum,
    float* __restrict__ out, int KS2)
{
    const int ND4 = N * D / 4;
    for (int i = bid * NTHR + tid; i < ND4; i += NBLK * NTHR) {
        int row = i >> 7;
        float inv = 1.0f / dsum[row];
        float4 acc = {0.f, 0.f, 0.f, 0.f};
        for (int c = 0; c < KS2; ++c) {
            ushort4 u = ((const ushort4*)(Opart + (size_t)c * N * D))[i];
            acc.x += bf2f(u.x); acc.y += bf2f(u.y);
            acc.z += bf2f(u.z); acc.w += bf2f(u.w);
        }
        acc.x *= inv; acc.y *= inv; acc.z *= inv; acc.w *= inv;
        ((float4*)out)[i] = acc;
    }
}

// ---------------- fused cooperative kernel ----------------
__global__ __launch_bounds__(NTHR, 2) void fused_kernel(
    const float* q, const float* hist, const float* times,
    const float* w1, const float* b1, const float* w2, const float* b2,
    unsigned short* Qblk, unsigned short* Kblk, unsigned short* Vblk,
    unsigned short* Pblk, float* dsum, unsigned short* Opart, float* out, int KS2)
{
    cg::grid_group grid = cg::this_grid();
    const int bid = blockIdx.x, tid = threadIdx.x;

    prep_phase(bid, tid, q, hist, Qblk, Kblk, Vblk, dsum);
    __threadfence();
    grid.sync();
    qk_phase(bid, tid, Qblk, Kblk, times, w1, b1, w2, b2, Pblk, dsum);
    __threadfence();
    grid.sync();
    pv_phase(bid, tid, Pblk, Vblk, Opart, KS2);
    __threadfence();
    grid.sync();
    reduce_phase(bid, tid, Opart, dsum, out, KS2);
}

// ---------------- fallback wrappers (4 dispatches) ----------------
__global__ __launch_bounds__(NTHR, 2) void prep_wrap(
    const float* q, const float* hist, unsigned short* Qblk,
    unsigned short* Kblk, unsigned short* Vblk, float* dsum)
{ prep_phase(blockIdx.x, threadIdx.x, q, hist, Qblk, Kblk, Vblk, dsum); }

__global__ __launch_bounds__(NTHR, 2) void qk_wrap(
    const unsigned short* Qblk, const unsigned short* Kblk, const float* times,
    const float* w1, const float* b1, const float* w2, const float* b2,
    unsigned short* Pblk, float* dsum)
{ qk_phase(blockIdx.x, threadIdx.x, Qblk, Kblk, times, w1, b1, w2, b2, Pblk, dsum); }

__global__ __launch_bounds__(NTHR, 2) void pv_wrap(
    const unsigned short* Pblk, const unsigned short* Vblk,
    unsigned short* Opart, int KS2)
{ pv_phase(blockIdx.x, threadIdx.x, Pblk, Vblk, Opart, KS2); }

__global__ __launch_bounds__(NTHR, 2) void reduce_wrap(
    const unsigned short* Opart, const float* dsum, float* out, int KS2)
{ reduce_phase(blockIdx.x, threadIdx.x, Opart, dsum, out, KS2); }

extern "C" void kernel_launch(void* const* d_in, const int* in_sizes, int n_in,
                              void* d_out, int out_size, void* d_ws, size_t ws_size,
                              hipStream_t stream) {
    const float* q     = (const float*)d_in[0];
    const float* hist  = (const float*)d_in[1];
    const float* times = (const float*)d_in[2];
    const float* w1    = (const float*)d_in[3];
    const float* b1    = (const float*)d_in[4];
    const float* w2    = (const float*)d_in[5];
    const float* b2    = (const float*)d_in[6];
    float* out = (float*)d_out;

    // ws: Vblk 4M | Pblk 32M | dsum 64K | [Qblk 4M | Kblk 4M ... Opart (KS2*4M)]
    // Opart aliases Qblk/Kblk — pv/reduce never read them (phase-ordered).
    char* base = (char*)d_ws;
    const size_t MB4 = (size_t)N * D * 2;
    unsigned short* Vblk = (unsigned short*)base;
    unsigned short* Pblk = (unsigned short*)(base + MB4);
    float* dsum          = (float*)(base + MB4 + (size_t)N * (size_t)N * 2);
    char* ob             = base + MB4 + (size_t)N * (size_t)N * 2 + 65536;
    unsigned short* Qblk = (unsigned short*)ob;
    unsigned short* Kblk = (unsigned short*)(ob + MB4);
    unsigned short* Opart = (unsigned short*)ob;
    const size_t fixed = (size_t)(ob - base);
    int KS2 = (ws_size >= fixed + 8 * MB4) ? 8 :
              (ws_size >= fixed + 4 * MB4) ? 4 : 2;

    hipFuncSetAttribute((const void*)fused_kernel,
                        hipFuncAttributeMaxDynamicSharedMemorySize, SMEM_BYTES);
    hipFuncSetAttribute((const void*)qk_wrap,
                        hipFuncAttributeMaxDynamicSharedMemorySize, SMEM_BYTES);
    hipFuncSetAttribute((const void*)prep_wrap,
                        hipFuncAttributeMaxDynamicSharedMemorySize, SMEM_BYTES);

    // cooperative path requires all 512 blocks co-resident (2 blocks/CU)
    int occ = 0;
    hipOccupancyMaxActiveBlocksPerMultiprocessor(&occ, (const void*)fused_kernel,
                                                 NTHR, SMEM_BYTES);
    if (occ >= 2) {
        void* args[] = {
            (void*)&q, (void*)&hist, (void*)&times, (void*)&w1, (void*)&b1,
            (void*)&w2, (void*)&b2, (void*)&Qblk, (void*)&Kblk, (void*)&Vblk,
            (void*)&Pblk, (void*)&dsum, (void*)&Opart, (void*)&out, (void*)&KS2
        };
        hipError_t e = hipLaunchCooperativeKernel((void*)fused_kernel,
                                                  dim3(NBLK), dim3(NTHR),
                                                  args, SMEM_BYTES, stream);
        if (e == hipSuccess) return;
        (void)hipGetLastError();   // clear; fall through to split path
    }

    prep_wrap<<<NBLK, NTHR, 32768, stream>>>(q, hist, Qblk, Kblk, Vblk, dsum);
    qk_wrap<<<NBLK, NTHR, SMEM_BYTES, stream>>>(Qblk, Kblk, times, w1, b1, w2, b2, Pblk, dsum);
    pv_wrap<<<NBLK, NTHR, 0, stream>>>(Pblk, Vblk, Opart, KS2);
    reduce_wrap<<<NBLK, NTHR, 0, stream>>>(Opart, dsum, out, KS2);
}

// Round 11
// 150.132 us; speedup vs baseline: 1.5437x; 1.0033x over previous
//
#include <hip/hip_runtime.h>

#define N 4096
#define D 512
#define FRAG_SH 512            // shorts per 16x32 MFMA fragment (1 KB)
#define NTHR 256
#define SC_STRIDE 136          // qk scratch row stride in shorts (272 B)
#define SMEM_BYTES 69632       // 4 waves * 64 rows * 136 shorts * 2 B

typedef __attribute__((ext_vector_type(8))) short short8;
typedef __attribute__((ext_vector_type(4))) float f32x4;

__device__ __forceinline__ unsigned short f2bf(float f) {
    unsigned int u = __float_as_uint(f);
    u = (u + 0x7FFFu + ((u >> 16) & 1u)) >> 16;
    return (unsigned short)u;
}
__device__ __forceinline__ unsigned short f2bf_rn(float f) {
    return (unsigned short)((__float_as_uint(f) + 0x8000u) >> 16);
}
__device__ __forceinline__ float bf2f(unsigned short u) {
    return __uint_as_float((unsigned)u << 16);
}

// ---------------- prep ----------------
// blocks [0,128): Q 32-row tile -> Qblk (A-frag-linear, pre-scaled 1/sqrt(D))
// blocks [128,256): hist 32-row tile -> Kblk (B-frag) + Vblk (B-frag)
// blocks [256,258): zero dsum
__global__ __launch_bounds__(NTHR) void prep_kernel(
    const float* __restrict__ q, const float* __restrict__ hist,
    unsigned short* __restrict__ Qblk, unsigned short* __restrict__ Kblk,
    unsigned short* __restrict__ Vblk, float* __restrict__ dsum)
{
    __shared__ unsigned short smem[32 * 512];
    const int bid = blockIdx.x, tid = threadIdx.x;
    if (bid >= 256) {
        int z = (bid - 256) * NTHR + tid;       // 0..511
        #pragma unroll
        for (int j = 0; j < 8; ++j) dsum[z * 8 + j] = 0.f;
        return;
    }
    const bool isQ = bid < 128;
    const int t = isQ ? bid : bid - 128;
    const float* src = isQ ? q : hist;
    const float scale = isQ ? 0.04419417382415922f : 1.0f;

    #pragma unroll
    for (int k = 0; k < 16; ++k) {
        int idx = tid + k * 256;
        int row = idx >> 7;
        int c4  = (idx & 127) << 2;
        float4 v = *(const float4*)(src + (size_t)(t * 32 + row) * D + c4);
        ushort4 o;
        o.x = f2bf(v.x * scale); o.y = f2bf(v.y * scale);
        o.z = f2bf(v.z * scale); o.w = f2bf(v.w * scale);
        *(ushort4*)(smem + row * 512 + c4) = o;
    }
    __syncthreads();

    unsigned short* ABdst = isQ ? Qblk : Kblk;
    #pragma unroll
    for (int k = 0; k < 8; ++k) {
        int s = tid + k * 256;
        int fl = s >> 6, ln = s & 63;
        int dk = fl >> 1, rbl = fl & 1;
        int l16 = ln & 15, qq = ln >> 4;
        short8 v = *(const short8*)(smem + (rbl * 16 + l16) * 512 + dk * 32 + qq * 8);
        *(short8*)(ABdst + ((size_t)dk * 256 + t * 2 + rbl) * FRAG_SH + ln * 8) = v;
    }
    if (!isQ) {
        #pragma unroll
        for (int k = 0; k < 8; ++k) {
            int s = tid + k * 256;
            int db = s >> 6, ln = s & 63;
            int l16 = ln & 15, qq = ln >> 4;
            unsigned short tmp[8];
            #pragma unroll
            for (int j = 0; j < 8; ++j)
                tmp[j] = smem[(qq * 8 + j) * 512 + db * 16 + l16];
            *(short8*)(Vblk + ((size_t)t * 32 + db) * FRAG_SH + ln * 8) = *(const short8*)tmp;
        }
    }
}

// ---------------- qk ----------------
// 512 blocks: rg = bid>>4 (128-row group), cg XCD-affine (256-col group).
// 4 waves, wave tile 64x128 (acc 4x8): 32 MFMA + 12 coalesced 1KB loads/iter,
// barrier-free; epilogue = collapsed-MLP tw*exp + row-sum atomics + C->A via
// wave-private LDS; P written frag-linear (frag = kb32*256 + rowfrag).
__global__ __launch_bounds__(NTHR, 2) void qk_kernel(
    const unsigned short* __restrict__ Qblk, const unsigned short* __restrict__ Kblk,
    const float* __restrict__ times,
    const float* __restrict__ w1, const float* __restrict__ b1,
    const float* __restrict__ w2, const float* __restrict__ b2,
    unsigned short* __restrict__ Pblk, float* __restrict__ dsum)
{
    extern __shared__ unsigned short smem[];
    const int tid = threadIdx.x, bid = blockIdx.x;
    const int wv = tid >> 6, lane = tid & 63;
    const int qq = lane >> 4, l16 = lane & 15;
    const int wy = wv >> 1, wx = wv & 1;
    const int cg = ((bid & 7) << 1) | ((bid >> 3) & 1);  // XCD-affine col group
    const int rg = bid >> 4;

    f32x4 acc[4][8];
    #pragma unroll
    for (int fy = 0; fy < 4; ++fy)
        #pragma unroll
        for (int fx = 0; fx < 8; ++fx) acc[fy][fx] = (f32x4){0.f, 0.f, 0.f, 0.f};

    for (int dk = 0; dk < 16; ++dk) {
        short8 a[4], b[8];
        #pragma unroll
        for (int fy = 0; fy < 4; ++fy)
            a[fy] = *(const short8*)(Qblk + ((size_t)dk * 256 + rg * 8 + wy * 4 + fy) * FRAG_SH + lane * 8);
        #pragma unroll
        for (int fx = 0; fx < 8; ++fx)
            b[fx] = *(const short8*)(Kblk + ((size_t)dk * 256 + cg * 16 + wx * 8 + fx) * FRAG_SH + lane * 8);
        #pragma unroll
        for (int fy = 0; fy < 4; ++fy)
            #pragma unroll
            for (int fx = 0; fx < 8; ++fx)
                acc[fy][fx] = __builtin_amdgcn_mfma_f32_16x16x32_bf16(a[fy], b[fx], acc[fy][fx], 0, 0, 0);
    }

    float w1v[8], b1v[8], w2v[8];
    #pragma unroll
    for (int k = 0; k < 8; ++k) { w1v[k] = w1[k]; b1v[k] = b1[k]; w2v[k] = w2[k]; }
    const float b2v = b2[0];
    bool fast = true;
    #pragma unroll
    for (int k = 0; k < 8; ++k) fast = fast && (b1v[k] == 0.0f);
    float C1 = 0.0f;
    #pragma unroll
    for (int k = 0; k < 8; ++k) C1 += w2v[k] * fmaxf(w1v[k], 0.0f);

    const int rowbase = rg * 128 + wy * 64;
    const int colbase = cg * 256 + wx * 128;
    float tcol[8];
    #pragma unroll
    for (int fx = 0; fx < 8; ++fx) tcol[fx] = times[colbase + fx * 16 + l16];

    unsigned short* sc = smem + wv * (64 * SC_STRIDE);   // wave-private 64x136
    #pragma unroll
    for (int fy = 0; fy < 4; ++fy) {
        #pragma unroll
        for (int ri = 0; ri < 4; ++ri) {
            const float tq = times[rowbase + fy * 16 + qq * 4 + ri];
            float se = 0.f;
            #pragma unroll
            for (int fx = 0; fx < 8; ++fx) {
                float td = fabsf(tq - tcol[fx]);
                float a = fmaf(td, C1, b2v);
                if (!fast) {
                    a = b2v;
                    #pragma unroll
                    for (int k = 0; k < 8; ++k)
                        a += w2v[k] * fmaxf(fmaf(td, w1v[k], b1v[k]), 0.f);
                }
                float twt = __builtin_amdgcn_rcpf(1.0f + __expf(-a));
                float e = __expf(acc[fy][fx][ri] * twt);   // 1/sqrt(D) folded into Q
                se += e;
                sc[(fy * 16 + qq * 4 + ri) * SC_STRIDE + fx * 16 + l16] = f2bf_rn(e);
            }
            se += __shfl_xor(se, 1);
            se += __shfl_xor(se, 2);
            se += __shfl_xor(se, 4);
            se += __shfl_xor(se, 8);
            if (l16 == 0) atomicAdd(dsum + rowbase + fy * 16 + qq * 4 + ri, se);
        }
    }
    #pragma unroll
    for (int fy = 0; fy < 4; ++fy)
        #pragma unroll
        for (int kb = 0; kb < 4; ++kb) {
            short8 v = *(const short8*)(sc + (fy * 16 + l16) * SC_STRIDE + kb * 32 + qq * 8);
            size_t fidx = (size_t)(cg * 8 + wx * 4 + kb) * 256 + (rg * 8 + wy * 4 + fy);
            *(short8*)(Pblk + fidx * FRAG_SH + lane * 8) = v;
        }
}

// ---------------- pv ----------------
// P-read-once: grid (KS2, 128). Block tile 32 rows x 512 cols (full D),
// 4 waves = 128-col strips, acc[2][8] (64 regs -> 2 blocks/CU). Each P A-frag
// (kb32, rowfrag=rg*2+fy) is read by exactly ONE block (L1-broadcast across
// its 4 waves). V (4 MB) is L2-resident. Barrier-free, no LDS.
__global__ __launch_bounds__(NTHR, 2) void pv_kernel(
    const unsigned short* __restrict__ Pblk, const unsigned short* __restrict__ Vblk,
    unsigned short* __restrict__ Opart, int iters)
{
    const int tid = threadIdx.x;
    const int wv = tid >> 6, lane = tid & 63;
    const int qq = lane >> 4, l16 = lane & 15;
    const int chunk = blockIdx.x;
    const int rg = blockIdx.y;            // 0..127: 32-row group
    const int kbase = chunk * iters;      // kb32 units

    f32x4 acc[2][8];
    #pragma unroll
    for (int fy = 0; fy < 2; ++fy)
        #pragma unroll
        for (int fx = 0; fx < 8; ++fx) acc[fy][fx] = (f32x4){0.f, 0.f, 0.f, 0.f};

    for (int it = 0; it < iters; ++it) {
        const int kb32 = kbase + it;
        short8 a[2], b[8];
        #pragma unroll
        for (int fy = 0; fy < 2; ++fy)
            a[fy] = *(const short8*)(Pblk + ((size_t)kb32 * 256 + rg * 2 + fy) * FRAG_SH + lane * 8);
        #pragma unroll
        for (int fx = 0; fx < 8; ++fx)
            b[fx] = *(const short8*)(Vblk + ((size_t)kb32 * 32 + wv * 8 + fx) * FRAG_SH + lane * 8);
        #pragma unroll
        for (int fy = 0; fy < 2; ++fy)
            #pragma unroll
            for (int fx = 0; fx < 8; ++fx)
                acc[fy][fx] = __builtin_amdgcn_mfma_f32_16x16x32_bf16(a[fy], b[fx], acc[fy][fx], 0, 0, 0);
    }

    unsigned short* ob = Opart + (size_t)chunk * N * D;
    #pragma unroll
    for (int fy = 0; fy < 2; ++fy)
        #pragma unroll
        for (int ri = 0; ri < 4; ++ri) {
            const int row = rg * 32 + fy * 16 + qq * 4 + ri;
            #pragma unroll
            for (int fx = 0; fx < 8; ++fx) {
                const int col = wv * 128 + fx * 16 + l16;
                ob[(size_t)row * D + col] = f2bf_rn(acc[fy][fx][ri]);
            }
        }
}

// ---------------- reduce ----------------
__global__ __launch_bounds__(NTHR) void reduce_kernel(
    const unsigned short* __restrict__ Opart, const float* __restrict__ dsum,
    float* __restrict__ out, int KS2)
{
    int i = blockIdx.x * NTHR + threadIdx.x;   // float4 index
    int row = i >> 7;
    float inv = 1.0f / dsum[row];
    float4 acc = {0.f, 0.f, 0.f, 0.f};
    for (int c = 0; c < KS2; ++c) {
        ushort4 u = ((const ushort4*)(Opart + (size_t)c * N * D))[i];
        acc.x += bf2f(u.x); acc.y += bf2f(u.y);
        acc.z += bf2f(u.z); acc.w += bf2f(u.w);
    }
    acc.x *= inv; acc.y *= inv; acc.z *= inv; acc.w *= inv;
    ((float4*)out)[i] = acc;
}

extern "C" void kernel_launch(void* const* d_in, const int* in_sizes, int n_in,
                              void* d_out, int out_size, void* d_ws, size_t ws_size,
                              hipStream_t stream) {
    const float* q     = (const float*)d_in[0];
    const float* hist  = (const float*)d_in[1];
    const float* times = (const float*)d_in[2];
    const float* w1    = (const float*)d_in[3];
    const float* b1    = (const float*)d_in[4];
    const float* w2    = (const float*)d_in[5];
    const float* b2    = (const float*)d_in[6];
    float* out = (float*)d_out;

    // ws: Vblk 4M | Pblk 32M | dsum 64K | Qblk 4M | Kblk 4M (Opart aliases Qblk)
    char* base = (char*)d_ws;
    const size_t MB4 = (size_t)N * D * 2;
    unsigned short* Vblk = (unsigned short*)base;
    unsigned short* Pblk = (unsigned short*)(base + MB4);
    float* dsum          = (float*)(base + MB4 + (size_t)N * (size_t)N * 2);
    char* ob             = base + MB4 + (size_t)N * (size_t)N * 2 + 65536;
    unsigned short* Qblk = (unsigned short*)ob;
    unsigned short* Kblk = (unsigned short*)(ob + MB4);
    unsigned short* Opart = (unsigned short*)ob;       // pv/reduce never read Q/K
    const size_t fixed = (size_t)(ob - base);
    const int KS2 = (ws_size >= fixed + 8 * MB4) ? 8 :
                    (ws_size >= fixed + 4 * MB4) ? 4 : 2;
    const int iters = (N / 32) / KS2;

    hipFuncSetAttribute((const void*)qk_kernel,
                        hipFuncAttributeMaxDynamicSharedMemorySize, SMEM_BYTES);

    prep_kernel<<<258, NTHR, 0, stream>>>(q, hist, Qblk, Kblk, Vblk, dsum);
    qk_kernel<<<512, NTHR, SMEM_BYTES, stream>>>(Qblk, Kblk, times, w1, b1, w2, b2, Pblk, dsum);
    pv_kernel<<<dim3(KS2, 128), NTHR, 0, stream>>>(Pblk, Vblk, Opart, iters);
    reduce_kernel<<<(N * D / 4) / NTHR, NTHR, 0, stream>>>(Opart, dsum, out, KS2);
}